// Round 1
// baseline (461.249 us; speedup 1.0000x reference)
//
#include <hip/hip_runtime.h>

// VoxelGrid trilinear sampling, MI355X.
// Grid: (200, 200, 50, 1) f32, lower=(-4,-4,-1), resolution=25.
// Outputs: sigma [N], alpha [N] (constant 0), concatenated in d_out.

constexpr int SX = 200, SY = 200, SZ = 50;

__global__ __launch_bounds__(256) void voxel_trilinear_kernel(
    const float* __restrict__ x,      // [N,3]
    const float* __restrict__ grid,   // [200,200,50]
    float* __restrict__ out,          // [2*N]: sigma | alpha
    int n)
{
    int i = blockIdx.x * 256 + threadIdx.x;
    if (i >= n) return;

    float px = x[3 * i + 0];
    float py = x[3 * i + 1];
    float pz = x[3 * i + 2];

    // fractional index: (x - lower) * resolution
    float ix = (px + 4.0f) * 25.0f;
    float iy = (py + 4.0f) * 25.0f;
    float iz = (pz + 1.0f) * 25.0f;

    bool valid = (ix >= 0.0f) & (ix <= (float)(SX - 1)) &
                 (iy >= 0.0f) & (iy <= (float)(SY - 1)) &
                 (iz >= 0.0f) & (iz <= (float)(SZ - 1));

    float fx = floorf(ix), fy = floorf(iy), fz = floorf(iz);

    int ax = min(max((int)fx, 0), SX - 1);
    int ay = min(max((int)fy, 0), SY - 1);
    int az = min(max((int)fz, 0), SZ - 1);
    int bx = min(ax + 1, SX - 1);
    int by = min(ay + 1, SY - 1);
    int bz = min(az + 1, SZ - 1);

    float tx = ix - fx, ty = iy - fy, tz = iz - fz;
    float sx = 1.0f - tx, sy = 1.0f - ty, sz = 1.0f - tz;

    // row bases (z-contiguous layout: ((x*SY)+y)*SZ + z)
    int r00 = (ax * SY + ay) * SZ;
    int r01 = (ax * SY + by) * SZ;
    int r10 = (bx * SY + ay) * SZ;
    int r11 = (bx * SY + by) * SZ;

    float v000 = grid[r00 + az], v001 = grid[r00 + bz];
    float v010 = grid[r01 + az], v011 = grid[r01 + bz];
    float v100 = grid[r10 + az], v101 = grid[r10 + bz];
    float v110 = grid[r11 + az], v111 = grid[r11 + bz];

    // factored trilinear (numerically within f32 noise of the 8-product sum)
    float c00 = v000 * sz + v001 * tz;
    float c01 = v010 * sz + v011 * tz;
    float c10 = v100 * sz + v101 * tz;
    float c11 = v110 * sz + v111 * tz;
    float c0 = c00 * sy + c01 * ty;
    float c1 = c10 * sy + c11 * ty;
    float acc = c0 * sx + c1 * tx;

    out[i] = valid ? acc : 0.0f;   // sigma
    out[n + i] = 0.0f;             // alpha (do_alpha=False)
}

extern "C" void kernel_launch(void* const* d_in, const int* in_sizes, int n_in,
                              void* d_out, int out_size, void* d_ws, size_t ws_size,
                              hipStream_t stream) {
    const float* x = (const float*)d_in[0];
    const float* grid = (const float*)d_in[1];
    float* out = (float*)d_out;
    int n = in_sizes[0] / 3;  // 8388608

    int blocks = (n + 255) / 256;
    voxel_trilinear_kernel<<<blocks, 256, 0, stream>>>(x, grid, out, n);
}

// Round 2
// 411.843 us; speedup vs baseline: 1.1200x; 1.1200x over previous
//
#include <hip/hip_runtime.h>
#include <hip/hip_fp16.h>

// VoxelGrid trilinear sampling, MI355X.
// Round 2: fp16 grid copy in d_ws (4 MB) -> fits per-XCD L2 (4 MiB) ->
// gather path becomes ~100% L2-hit instead of 55% (8 MB f32 grid vs 4 MB L2).
// Grid: (200, 200, 50, 1), lower=(-4,-4,-1), resolution=25.
// Outputs: sigma [N], alpha [N] (constant 0), concatenated in d_out.

constexpr int SX = 200, SY = 200, SZ = 50;
constexpr int NVOX = SX * SY * SZ;  // 2,000,000

__global__ __launch_bounds__(256) void convert_grid_fp16(
    const float* __restrict__ grid, __half* __restrict__ t)
{
    int i = blockIdx.x * 256 + threadIdx.x;
    // grid-stride not needed: launch exact size
    if (i < NVOX) t[i] = __float2half(grid[i]);
}

__global__ __launch_bounds__(256) void voxel_trilinear_fp16(
    const float* __restrict__ x,      // [N,3]
    const __half* __restrict__ t,     // [200*200*50] fp16 table
    float* __restrict__ out,          // [2*N]: sigma | alpha
    int n)
{
    int i = blockIdx.x * 256 + threadIdx.x;
    if (i >= n) return;

    float px = x[3 * i + 0];
    float py = x[3 * i + 1];
    float pz = x[3 * i + 2];

    float ix = (px + 4.0f) * 25.0f;
    float iy = (py + 4.0f) * 25.0f;
    float iz = (pz + 1.0f) * 25.0f;

    bool valid = (ix >= 0.0f) & (ix <= (float)(SX - 1)) &
                 (iy >= 0.0f) & (iy <= (float)(SY - 1)) &
                 (iz >= 0.0f) & (iz <= (float)(SZ - 1));

    float fx = floorf(ix), fy = floorf(iy), fz = floorf(iz);

    int ax = min(max((int)fx, 0), SX - 1);
    int ay = min(max((int)fy, 0), SY - 1);
    int az = min(max((int)fz, 0), SZ - 1);
    int bx = min(ax + 1, SX - 1);
    int by = min(ay + 1, SY - 1);
    int bz = min(az + 1, SZ - 1);

    float tx = ix - fx, ty = iy - fy, tz = iz - fz;
    float sx = 1.0f - tx, sy = 1.0f - ty, szf = 1.0f - tz;

    int r00 = (ax * SY + ay) * SZ;
    int r01 = (ax * SY + by) * SZ;
    int r10 = (bx * SY + ay) * SZ;
    int r11 = (bx * SY + by) * SZ;

    float v000 = __half2float(t[r00 + az]), v001 = __half2float(t[r00 + bz]);
    float v010 = __half2float(t[r01 + az]), v011 = __half2float(t[r01 + bz]);
    float v100 = __half2float(t[r10 + az]), v101 = __half2float(t[r10 + bz]);
    float v110 = __half2float(t[r11 + az]), v111 = __half2float(t[r11 + bz]);

    float c00 = v000 * szf + v001 * tz;
    float c01 = v010 * szf + v011 * tz;
    float c10 = v100 * szf + v101 * tz;
    float c11 = v110 * szf + v111 * tz;
    float c0 = c00 * sy + c01 * ty;
    float c1 = c10 * sy + c11 * ty;
    float acc = c0 * sx + c1 * tx;

    out[i] = valid ? acc : 0.0f;   // sigma
    out[n + i] = 0.0f;             // alpha
}

// Fallback (round-1 kernel) in case ws_size < 4 MB.
__global__ __launch_bounds__(256) void voxel_trilinear_f32(
    const float* __restrict__ x, const float* __restrict__ grid,
    float* __restrict__ out, int n)
{
    int i = blockIdx.x * 256 + threadIdx.x;
    if (i >= n) return;
    float px = x[3 * i], py = x[3 * i + 1], pz = x[3 * i + 2];
    float ix = (px + 4.0f) * 25.0f;
    float iy = (py + 4.0f) * 25.0f;
    float iz = (pz + 1.0f) * 25.0f;
    bool valid = (ix >= 0.0f) & (ix <= (float)(SX - 1)) &
                 (iy >= 0.0f) & (iy <= (float)(SY - 1)) &
                 (iz >= 0.0f) & (iz <= (float)(SZ - 1));
    float fx = floorf(ix), fy = floorf(iy), fz = floorf(iz);
    int ax = min(max((int)fx, 0), SX - 1);
    int ay = min(max((int)fy, 0), SY - 1);
    int az = min(max((int)fz, 0), SZ - 1);
    int bx = min(ax + 1, SX - 1);
    int by = min(ay + 1, SY - 1);
    int bz = min(az + 1, SZ - 1);
    float tx = ix - fx, ty = iy - fy, tz = iz - fz;
    float sx = 1.0f - tx, sy = 1.0f - ty, szf = 1.0f - tz;
    int r00 = (ax * SY + ay) * SZ, r01 = (ax * SY + by) * SZ;
    int r10 = (bx * SY + ay) * SZ, r11 = (bx * SY + by) * SZ;
    float v000 = grid[r00 + az], v001 = grid[r00 + bz];
    float v010 = grid[r01 + az], v011 = grid[r01 + bz];
    float v100 = grid[r10 + az], v101 = grid[r10 + bz];
    float v110 = grid[r11 + az], v111 = grid[r11 + bz];
    float c00 = v000 * szf + v001 * tz;
    float c01 = v010 * szf + v011 * tz;
    float c10 = v100 * szf + v101 * tz;
    float c11 = v110 * szf + v111 * tz;
    float c0 = c00 * sy + c01 * ty;
    float c1 = c10 * sy + c11 * ty;
    out[i] = valid ? (c0 * sx + c1 * tx) : 0.0f;
    out[n + i] = 0.0f;
}

extern "C" void kernel_launch(void* const* d_in, const int* in_sizes, int n_in,
                              void* d_out, int out_size, void* d_ws, size_t ws_size,
                              hipStream_t stream) {
    const float* x = (const float*)d_in[0];
    const float* grid = (const float*)d_in[1];
    float* out = (float*)d_out;
    int n = in_sizes[0] / 3;  // 8388608
    int blocks = (n + 255) / 256;

    if (ws_size >= (size_t)NVOX * sizeof(__half)) {
        __half* t = (__half*)d_ws;
        convert_grid_fp16<<<(NVOX + 255) / 256, 256, 0, stream>>>(grid, t);
        voxel_trilinear_fp16<<<blocks, 256, 0, stream>>>(x, t, out, n);
    } else {
        voxel_trilinear_f32<<<blocks, 256, 0, stream>>>(x, grid, out, n);
    }
}

// Round 3
// 293.442 us; speedup vs baseline: 1.5719x; 1.4035x over previous
//
#include <hip/hip_runtime.h>
#include <hip/hip_fp16.h>

// VoxelGrid trilinear sampling, MI355X.
// Round 3: fp16 table (L2-resident, 4 MB) + paired-z gathers:
// the two z-corners are adjacent halfs -> one unaligned 4 B load each,
// cutting random gathers from 8 to 4 per point (TA/L1-lookup-rate bound).

constexpr int SX = 200, SY = 200, SZ = 50;
constexpr int NVOX = SX * SY * SZ;  // 2,000,000

__global__ __launch_bounds__(256) void convert_grid_fp16(
    const float* __restrict__ grid, __half* __restrict__ t)
{
    int i = blockIdx.x * 256 + threadIdx.x;
    if (i < NVOX) t[i] = __float2half(grid[i]);
}

// Unaligned (2-byte-aligned) 4-byte load of a z-adjacent half pair.
// gfx950 unaligned-access-mode lowers this to a single global_load_dword.
__device__ __forceinline__ float2 ldpair(const __half* __restrict__ t, int idx)
{
    __half2 h;
    __builtin_memcpy(&h, t + idx, sizeof(__half2));
    return __half22float2(h);
}

__global__ __launch_bounds__(256) void voxel_trilinear_pair(
    const float* __restrict__ x,      // [N,3]
    const __half* __restrict__ t,     // [200*200*50] fp16 table
    float* __restrict__ out,          // [2*N]: sigma | alpha
    int n)
{
    int i = blockIdx.x * 256 + threadIdx.x;
    if (i >= n) return;

    float ix = (x[3 * i + 0] + 4.0f) * 25.0f;
    float iy = (x[3 * i + 1] + 4.0f) * 25.0f;
    float iz = (x[3 * i + 2] + 1.0f) * 25.0f;

    bool valid = (ix >= 0.0f) & (ix <= (float)(SX - 1)) &
                 (iy >= 0.0f) & (iy <= (float)(SY - 1)) &
                 (iz >= 0.0f) & (iz <= (float)(SZ - 1));

    float fx = floorf(ix), fy = floorf(iy), fz = floorf(iz);

    int ax = min(max((int)fx, 0), SX - 1);
    int ay = min(max((int)fy, 0), SY - 1);
    int bx = min(ax + 1, SX - 1);
    int by = min(ay + 1, SY - 1);

    // z pair base clamped to SZ-2: for az<=SZ-2, u = tz; for az==SZ-1
    // (iz exactly at the top edge, tz==0), u == 1.0 selects pair.y == v[SZ-1].
    int zc = min(max((int)fz, 0), SZ - 2);
    float u = iz - (float)zc;
    float su = 1.0f - u;

    float tx = ix - fx, ty = iy - fy;
    float sx = 1.0f - tx, sy = 1.0f - ty;

    int r00 = (ax * SY + ay) * SZ + zc;
    int r01 = (ax * SY + by) * SZ + zc;
    int r10 = (bx * SY + ay) * SZ + zc;
    int r11 = (bx * SY + by) * SZ + zc;

    float2 p00 = ldpair(t, r00);
    float2 p01 = ldpair(t, r01);
    float2 p10 = ldpair(t, r10);
    float2 p11 = ldpair(t, r11);

    float c00 = p00.x * su + p00.y * u;
    float c01 = p01.x * su + p01.y * u;
    float c10 = p10.x * su + p10.y * u;
    float c11 = p11.x * su + p11.y * u;
    float c0 = c00 * sy + c01 * ty;
    float c1 = c10 * sy + c11 * ty;
    float acc = c0 * sx + c1 * tx;

    out[i] = valid ? acc : 0.0f;   // sigma
    out[n + i] = 0.0f;             // alpha (do_alpha=False)
}

// Fallback (round-1 style) in case ws_size < 4 MB.
__global__ __launch_bounds__(256) void voxel_trilinear_f32(
    const float* __restrict__ x, const float* __restrict__ grid,
    float* __restrict__ out, int n)
{
    int i = blockIdx.x * 256 + threadIdx.x;
    if (i >= n) return;
    float ix = (x[3 * i] + 4.0f) * 25.0f;
    float iy = (x[3 * i + 1] + 4.0f) * 25.0f;
    float iz = (x[3 * i + 2] + 1.0f) * 25.0f;
    bool valid = (ix >= 0.0f) & (ix <= (float)(SX - 1)) &
                 (iy >= 0.0f) & (iy <= (float)(SY - 1)) &
                 (iz >= 0.0f) & (iz <= (float)(SZ - 1));
    float fx = floorf(ix), fy = floorf(iy), fz = floorf(iz);
    int ax = min(max((int)fx, 0), SX - 1);
    int ay = min(max((int)fy, 0), SY - 1);
    int az = min(max((int)fz, 0), SZ - 1);
    int bx = min(ax + 1, SX - 1);
    int by = min(ay + 1, SY - 1);
    int bz = min(az + 1, SZ - 1);
    float tx = ix - fx, ty = iy - fy, tz = iz - fz;
    float sx = 1.0f - tx, sy = 1.0f - ty, szf = 1.0f - tz;
    int r00 = (ax * SY + ay) * SZ, r01 = (ax * SY + by) * SZ;
    int r10 = (bx * SY + ay) * SZ, r11 = (bx * SY + by) * SZ;
    float v000 = grid[r00 + az], v001 = grid[r00 + bz];
    float v010 = grid[r01 + az], v011 = grid[r01 + bz];
    float v100 = grid[r10 + az], v101 = grid[r10 + bz];
    float v110 = grid[r11 + az], v111 = grid[r11 + bz];
    float c00 = v000 * szf + v001 * tz;
    float c01 = v010 * szf + v011 * tz;
    float c10 = v100 * szf + v101 * tz;
    float c11 = v110 * szf + v111 * tz;
    float c0 = c00 * sy + c01 * ty;
    float c1 = c10 * sy + c11 * ty;
    out[i] = valid ? (c0 * sx + c1 * tx) : 0.0f;
    out[n + i] = 0.0f;
}

extern "C" void kernel_launch(void* const* d_in, const int* in_sizes, int n_in,
                              void* d_out, int out_size, void* d_ws, size_t ws_size,
                              hipStream_t stream) {
    const float* x = (const float*)d_in[0];
    const float* grid = (const float*)d_in[1];
    float* out = (float*)d_out;
    int n = in_sizes[0] / 3;  // 8388608
    int blocks = (n + 255) / 256;

    if (ws_size >= (size_t)NVOX * sizeof(__half)) {
        __half* t = (__half*)d_ws;
        convert_grid_fp16<<<(NVOX + 255) / 256, 256, 0, stream>>>(grid, t);
        voxel_trilinear_pair<<<blocks, 256, 0, stream>>>(x, t, out, n);
    } else {
        voxel_trilinear_f32<<<blocks, 256, 0, stream>>>(x, grid, out, n);
    }
}

// Round 4
// 289.394 us; speedup vs baseline: 1.5938x; 1.0140x over previous
//
#include <hip/hip_runtime.h>
#include <hip/hip_fp16.h>

// VoxelGrid trilinear sampling, MI355X.
// Round 4: cell-centric fp16 table — one 16 B record per cell holding all
// 8 corners -> ONE dwordx4 gather per point (was 4 dword gathers), plus
// LDS-staged float4 reads of x. Kernel is TA/L1-lookup-rate bound; this
// cuts lookups/wave ~300 -> ~84.

constexpr int SX = 200, SY = 200, SZ = 50;
constexpr int NVOX = SX * SY * SZ;            // 2,000,000
constexpr int CX = SX - 1, CY = SY - 1, CZ = SZ - 1;  // 199,199,49
constexpr int NCELL = CX * CY * CZ;           // 1,940,449
// record layout (z fastest): v000 v001 | v010 v011 | v100 v101 | v110 v111

__global__ __launch_bounds__(256) void build_cells(
    const float* __restrict__ grid, uint4* __restrict__ rec)
{
    int i = blockIdx.x * 256 + threadIdx.x;
    if (i >= NCELL) return;
    int cz = i % CZ;
    int tmp = i / CZ;
    int cy = tmp % CY;
    int cx = tmp / CY;

    const float* g00 = grid + (cx * SY + cy) * SZ + cz;
    const float* g01 = g00 + SZ;        // y+1
    const float* g10 = g00 + SY * SZ;   // x+1
    const float* g11 = g10 + SZ;

    union { __half2 h[4]; uint4 u; } p;
    p.h[0] = __floats2half2_rn(g00[0], g00[1]);
    p.h[1] = __floats2half2_rn(g01[0], g01[1]);
    p.h[2] = __floats2half2_rn(g10[0], g10[1]);
    p.h[3] = __floats2half2_rn(g11[0], g11[1]);
    rec[i] = p.u;
}

__global__ __launch_bounds__(256) void voxel_trilinear_cell(
    const float* __restrict__ x,      // [N,3]
    const uint4* __restrict__ rec,    // [NCELL] packed cell records
    float* __restrict__ out,          // [2*N]: sigma | alpha
    int n)
{
    __shared__ float xs[768];         // 256 points * 3 floats
    int tid = threadIdx.x;
    int i = blockIdx.x * 256 + tid;

    // cooperative float4 staging of this block's x slice (3072 B)
    int base = blockIdx.x * 768;      // float offset
    if (tid < 192 && (base + 4 * tid + 3) < 3 * n) {
        float4 v = ((const float4*)(x + base))[tid];
        ((float4*)xs)[tid] = v;
    }
    __syncthreads();
    if (i >= n) return;

    float ix = (xs[3 * tid + 0] + 4.0f) * 25.0f;
    float iy = (xs[3 * tid + 1] + 4.0f) * 25.0f;
    float iz = (xs[3 * tid + 2] + 1.0f) * 25.0f;

    bool valid = (ix >= 0.0f) & (ix <= (float)(SX - 1)) &
                 (iy >= 0.0f) & (iy <= (float)(SY - 1)) &
                 (iz >= 0.0f) & (iz <= (float)(SZ - 1));

    // cell index clamped to [0, size-2]; u in [0,1] for in-range points,
    // u==1 at the exact top edge selects the upper corner (matches ref).
    int cx = min(max((int)floorf(ix), 0), SX - 2);
    int cy = min(max((int)floorf(iy), 0), SY - 2);
    int cz = min(max((int)floorf(iz), 0), SZ - 2);
    float ux = ix - (float)cx, uy = iy - (float)cy, uz = iz - (float)cz;
    float vx = 1.0f - ux, vy = 1.0f - uy, vz = 1.0f - uz;

    int cell = (cx * CY + cy) * CZ + cz;
    union { uint4 u; __half2 h[4]; } p;
    p.u = rec[cell];
    float2 f00 = __half22float2(p.h[0]);  // (x0,y0): v000,v001
    float2 f01 = __half22float2(p.h[1]);  // (x0,y1)
    float2 f10 = __half22float2(p.h[2]);  // (x1,y0)
    float2 f11 = __half22float2(p.h[3]);  // (x1,y1)

    float c00 = f00.x * vz + f00.y * uz;
    float c01 = f01.x * vz + f01.y * uz;
    float c10 = f10.x * vz + f10.y * uz;
    float c11 = f11.x * vz + f11.y * uz;
    float c0 = c00 * vy + c01 * uy;
    float c1 = c10 * vy + c11 * uy;
    float acc = c0 * vx + c1 * ux;

    out[i] = valid ? acc : 0.0f;   // sigma
    out[n + i] = 0.0f;             // alpha (do_alpha=False)
}

// ---- Round-3 fallback (fp16 z-pair table, 4 MB) ----
__global__ __launch_bounds__(256) void convert_grid_fp16(
    const float* __restrict__ grid, __half* __restrict__ t)
{
    int i = blockIdx.x * 256 + threadIdx.x;
    if (i < NVOX) t[i] = __float2half(grid[i]);
}

__device__ __forceinline__ float2 ldpair(const __half* __restrict__ t, int idx)
{
    __half2 h;
    __builtin_memcpy(&h, t + idx, sizeof(__half2));
    return __half22float2(h);
}

__global__ __launch_bounds__(256) void voxel_trilinear_pair(
    const float* __restrict__ x, const __half* __restrict__ t,
    float* __restrict__ out, int n)
{
    int i = blockIdx.x * 256 + threadIdx.x;
    if (i >= n) return;
    float ix = (x[3 * i + 0] + 4.0f) * 25.0f;
    float iy = (x[3 * i + 1] + 4.0f) * 25.0f;
    float iz = (x[3 * i + 2] + 1.0f) * 25.0f;
    bool valid = (ix >= 0.0f) & (ix <= (float)(SX - 1)) &
                 (iy >= 0.0f) & (iy <= (float)(SY - 1)) &
                 (iz >= 0.0f) & (iz <= (float)(SZ - 1));
    float fx = floorf(ix), fy = floorf(iy), fz = floorf(iz);
    int ax = min(max((int)fx, 0), SX - 1);
    int ay = min(max((int)fy, 0), SY - 1);
    int bx = min(ax + 1, SX - 1);
    int by = min(ay + 1, SY - 1);
    int zc = min(max((int)fz, 0), SZ - 2);
    float u = iz - (float)zc, su = 1.0f - u;
    float tx = ix - fx, ty = iy - fy;
    float sx = 1.0f - tx, sy = 1.0f - ty;
    int r00 = (ax * SY + ay) * SZ + zc;
    int r01 = (ax * SY + by) * SZ + zc;
    int r10 = (bx * SY + ay) * SZ + zc;
    int r11 = (bx * SY + by) * SZ + zc;
    float2 p00 = ldpair(t, r00), p01 = ldpair(t, r01);
    float2 p10 = ldpair(t, r10), p11 = ldpair(t, r11);
    float c00 = p00.x * su + p00.y * u;
    float c01 = p01.x * su + p01.y * u;
    float c10 = p10.x * su + p10.y * u;
    float c11 = p11.x * su + p11.y * u;
    float c0 = c00 * sy + c01 * ty;
    float c1 = c10 * sy + c11 * ty;
    out[i] = valid ? (c0 * sx + c1 * tx) : 0.0f;
    out[n + i] = 0.0f;
}

extern "C" void kernel_launch(void* const* d_in, const int* in_sizes, int n_in,
                              void* d_out, int out_size, void* d_ws, size_t ws_size,
                              hipStream_t stream) {
    const float* x = (const float*)d_in[0];
    const float* grid = (const float*)d_in[1];
    float* out = (float*)d_out;
    int n = in_sizes[0] / 3;  // 8388608
    int blocks = (n + 255) / 256;

    if (ws_size >= (size_t)NCELL * sizeof(uint4)) {
        uint4* rec = (uint4*)d_ws;
        build_cells<<<(NCELL + 255) / 256, 256, 0, stream>>>(grid, rec);
        voxel_trilinear_cell<<<blocks, 256, 0, stream>>>(x, rec, out, n);
    } else if (ws_size >= (size_t)NVOX * sizeof(__half)) {
        __half* t = (__half*)d_ws;
        convert_grid_fp16<<<(NVOX + 255) / 256, 256, 0, stream>>>(grid, t);
        voxel_trilinear_pair<<<blocks, 256, 0, stream>>>(x, t, out, n);
    }
}